// Round 3
// baseline (86.403 us; speedup 1.0000x reference)
//
#include <hip/hip_runtime.h>

// db4 decomposition low-pass
static constexpr float H0 = -0.010597401784997278f;
static constexpr float H1 =  0.032883011666982945f;
static constexpr float H2 =  0.030841381835986965f;
static constexpr float H3 = -0.18703481171888114f;
static constexpr float H4 = -0.02798376941698385f;
static constexpr float H5 =  0.6308807679295904f;
static constexpr float H6 =  0.7148465705525415f;
static constexpr float H7 =  0.23037781330885523f;

// Correlation weights, per-level 0.5 folded in (exact pow2 scale).
static constexpr float W0[8] = { 0.5f*H0,  0.5f*H1,  0.5f*H2,  0.5f*H3,
                                 0.5f*H4,  0.5f*H5,  0.5f*H6,  0.5f*H7 };
static constexpr float W1[8] = {-0.5f*H7,  0.5f*H6, -0.5f*H5,  0.5f*H4,
                                -0.5f*H3,  0.5f*H2, -0.5f*H1,  0.5f*H0 };

constexpr int T     = 4096;
constexpr int TILE  = 1024;   // outputs per block
constexpr int SG    = 272;    // staged granules per band (256 + 16 halo)
constexpr int BANDF = 1360;   // padded floats per band buffer

// padded float index of local granule g (pad one 4-float granule every 4)
static __device__ __forceinline__ int paddr(int g) { return (g << 2) + ((g >> 2) << 2); }

// Compute one output granule lg (4 outputs) of one inverse level.
// out[4lg+i] = sum_k W0[k]*LO[4lg + i + D(k-4)] + W1[k]*HI[...]
// window granules [lg-D, lg-D+NG); wl index = i + D*k.
template <int D, int NG>
static __device__ __forceinline__ void level1g(const float* __restrict__ lo,
                                               const float* __restrict__ hi,
                                               int lg, float res[4])
{
    float wl[NG * 4], wh[NG * 4];
#pragma unroll
    for (int j = 0; j < NG; ++j) {
        const int a = paddr(lg - D + j);
        const float4 vl = *(const float4*)(lo + a);
        const float4 vh = *(const float4*)(hi + a);
        wl[4 * j + 0] = vl.x; wl[4 * j + 1] = vl.y; wl[4 * j + 2] = vl.z; wl[4 * j + 3] = vl.w;
        wh[4 * j + 0] = vh.x; wh[4 * j + 1] = vh.y; wh[4 * j + 2] = vh.z; wh[4 * j + 3] = vh.w;
    }
#pragma unroll
    for (int i = 0; i < 4; ++i) {
        float acc = 0.0f;
#pragma unroll
        for (int k = 0; k < 8; ++k) {
            acc = fmaf(W0[k], wl[i + D * k], acc);
            acc = fmaf(W1[k], wh[i + D * k], acc);
        }
        res[i] = acc;
    }
}

static __device__ __forceinline__ void wr4(float* __restrict__ dst, int lg, const float r[4])
{
    *(float4*)(dst + paddr(lg)) = make_float4(r[0], r[1], r[2], r[3]);
}

__global__ __launch_bounds__(256, 5)
void iswt_kernel(const float* __restrict__ in, float* __restrict__ out)
{
    __shared__ float lds[4][BANDF];   // 21.25 KB -> 5 blocks/CU (VGPR-bound via launch_bounds)

    const int tid  = threadIdx.x;
    const int bid  = blockIdx.x;
    const int row  = bid >> 2;
    const int t0   = (bid & 3) << 10;          // tile start position in row

    // ---- stage: 1088 positions = [t0-32, t0+1056) wrapped, deinterleave 4 bands ----
    const float4* __restrict__ src = (const float4*)(in + (size_t)row * (T * 4));
#pragma unroll
    for (int j = 0; j < 4; ++j) {
        const int fp = tid + (j << 8);                 // local float position
        const int P  = (t0 - 32 + fp) & (T - 1);      // global position (wrap)
        const float4 v = src[P];
        const int a  = fp + ((fp >> 4) << 2);         // padded scalar index
        lds[0][a] = v.x; lds[1][a] = v.y; lds[2][a] = v.z; lds[3][a] = v.w;
    }
    if (tid < 64) {
        const int fp = 1024 + tid;
        const int P  = (t0 - 32 + fp) & (T - 1);
        const float4 v = src[P];
        const int a  = fp + ((fp >> 4) << 2);
        lds[0][a] = v.x; lds[1][a] = v.y; lds[2][a] = v.z; lds[3][a] = v.w;
    }
    __syncthreads();

    // ---- Level 1: lo=band3 (cD_1), hi=band2 (cD_2), D=4; compute granules [4,268) ----
    float ra[4], rb[4];
    level1g<4, 8>(&lds[3][0], &lds[2][0], 4 + tid, ra);
    if (tid < 8) level1g<4, 8>(&lds[3][0], &lds[2][0], 260 + tid, rb);
    __syncthreads();
    wr4(&lds[3][0], 4 + tid, ra);
    if (tid < 8) wr4(&lds[3][0], 260 + tid, rb);
    __syncthreads();

    // ---- Level 2: lo=res1 (buf3), hi=band1 (cD_3), D=2; compute granules [6,266) ----
    level1g<2, 5>(&lds[3][0], &lds[1][0], 6 + tid, ra);
    if (tid < 4) level1g<2, 5>(&lds[3][0], &lds[1][0], 262 + tid, rb);
    __syncthreads();
    wr4(&lds[1][0], 6 + tid, ra);
    if (tid < 4) wr4(&lds[1][0], 262 + tid, rb);
    __syncthreads();

    // ---- Level 3: lo=res2 (buf1), hi=band0 (cA_3), D=1; granules [8,264) -> global ----
    float r3[4];
    level1g<1, 3>(&lds[1][0], &lds[0][0], 8 + tid, r3);
    *(float4*)(out + (size_t)row * T + t0 + (tid << 2)) =
        make_float4(r3[0], r3[1], r3[2], r3[3]);
}

extern "C" void kernel_launch(void* const* d_in, const int* in_sizes, int n_in,
                              void* d_out, int out_size, void* d_ws, size_t ws_size,
                              hipStream_t stream)
{
    const float* coeffs = (const float*)d_in[0];
    float* out = (float*)d_out;
    const int nrows = in_sizes[0] / (T * 4);   // 4096
    iswt_kernel<<<nrows * 4, 256, 0, stream>>>(coeffs, out);
}

// Round 4
// 67.046 us; speedup vs baseline: 1.2887x; 1.2887x over previous
//
#include <hip/hip_runtime.h>

// db4 decomposition low-pass
static constexpr float H0 = -0.010597401784997278f;
static constexpr float H1 =  0.032883011666982945f;
static constexpr float H2 =  0.030841381835986965f;
static constexpr float H3 = -0.18703481171888114f;
static constexpr float H4 = -0.02798376941698385f;
static constexpr float H5 =  0.6308807679295904f;
static constexpr float H6 =  0.7148465705525415f;
static constexpr float H7 =  0.23037781330885523f;

// Correlation weights, per-level 0.5 folded in (exact pow2 scale).
static constexpr float W0[8] = { 0.5f*H0,  0.5f*H1,  0.5f*H2,  0.5f*H3,
                                 0.5f*H4,  0.5f*H5,  0.5f*H6,  0.5f*H7 };
static constexpr float W1[8] = {-0.5f*H7,  0.5f*H6, -0.5f*H5,  0.5f*H4,
                                -0.5f*H3,  0.5f*H2, -0.5f*H1,  0.5f*H0 };

constexpr int T     = 4096;
constexpr int SPOS  = 2100;   // staged float positions per band (525 granules)
constexpr int BANDF = 2624;   // padded floats per band buffer (gaddr(524)+4)

// padded float index: +4 floats per 16 (one pad granule per 4 granules)
static __device__ __forceinline__ int paddr_g(int g) { return (g << 2) + ((g >> 2) << 2); }
static __device__ __forceinline__ int paddr_f(int f) { return f + ((f >> 4) << 2); }

// Compute 2 output granules (8 floats) at local granule base lg.
// out[4lg + j] = sum_k W0[k]*LO[4lg + j + D(k-4)] + W1[k]*HI[...]
// window granules [lg-D, lg-D+NG); wl index = j + D*k  (max 7+7D <= 4*NG).
template <int D, int NG>
static __device__ __forceinline__ void level2g(const float* __restrict__ lo,
                                               const float* __restrict__ hi,
                                               int lg, float res[8])
{
    float wl[NG * 4], wh[NG * 4];
#pragma unroll
    for (int j = 0; j < NG; ++j) {
        const int a = paddr_g(lg - D + j);
        const float4 vl = *(const float4*)(lo + a);
        const float4 vh = *(const float4*)(hi + a);
        wl[4 * j + 0] = vl.x; wl[4 * j + 1] = vl.y; wl[4 * j + 2] = vl.z; wl[4 * j + 3] = vl.w;
        wh[4 * j + 0] = vh.x; wh[4 * j + 1] = vh.y; wh[4 * j + 2] = vh.z; wh[4 * j + 3] = vh.w;
    }
#pragma unroll
    for (int j = 0; j < 8; ++j) {
        float acc = 0.0f;
#pragma unroll
        for (int k = 0; k < 8; ++k) {
            acc = fmaf(W0[k], wl[j + D * k], acc);
            acc = fmaf(W1[k], wh[j + D * k], acc);
        }
        res[j] = acc;
    }
}

static __device__ __forceinline__ void wr2g(float* __restrict__ dst, int lg, const float r[8])
{
    *(float4*)(dst + paddr_g(lg))     = make_float4(r[0], r[1], r[2], r[3]);
    *(float4*)(dst + paddr_g(lg + 1)) = make_float4(r[4], r[5], r[6], r[7]);
}

__global__ __launch_bounds__(256, 3)
void iswt_kernel(const float* __restrict__ in, float* __restrict__ out)
{
    __shared__ float lds[5][BANDF];   // 52.5 KB -> 3 blocks/CU

    const int tid = threadIdx.x;
    const int bid = blockIdx.x;
    const int row = bid >> 1;
    const int t0  = (bid & 1) << 11;          // tile start (0 or 2048)

    // ---- stage: positions [t0-28, t0+2072) wrapped; deinterleave 4 bands ----
    const float4* __restrict__ src = (const float4*)(in + (size_t)row * (T * 4));
#pragma unroll
    for (int j = 0; j < 8; ++j) {
        const int fp = tid + (j << 8);
        const int P  = (t0 - 28 + fp) & (T - 1);
        const float4 v = src[P];
        const int a  = paddr_f(fp);
        lds[0][a] = v.x; lds[1][a] = v.y; lds[2][a] = v.z; lds[3][a] = v.w;
    }
    if (tid < SPOS - 2048) {                  // 52-position tail
        const int fp = 2048 + tid;
        const int P  = (t0 - 28 + fp) & (T - 1);
        const float4 v = src[P];
        const int a  = paddr_f(fp);
        lds[0][a] = v.x; lds[1][a] = v.y; lds[2][a] = v.z; lds[3][a] = v.w;
    }
    __syncthreads();

    float r[8];

    // ---- Level 1: lo=buf3 (cD_1), hi=buf2 (cD_2), D=4 -> r1 in buf4 over [4,522) ----
    level2g<4, 9>(&lds[3][0], &lds[2][0], 4 + 2 * tid, r);
    wr2g(&lds[4][0], 4 + 2 * tid, r);
    if (tid < 3) {                            // tail granules [516,522)
        float rt[8];
        level2g<4, 9>(&lds[3][0], &lds[2][0], 516 + 2 * tid, rt);
        wr2g(&lds[4][0], 516 + 2 * tid, rt);
    }
    __syncthreads();

    // ---- Level 2: lo=buf4 (r1), hi=buf1 (cD_3), D=2 -> r2 in buf3 over [6,520) ----
    level2g<2, 6>(&lds[4][0], &lds[1][0], 6 + 2 * tid, r);
    wr2g(&lds[3][0], 6 + 2 * tid, r);
    if (tid == 0) {                           // tail granules [518,520)
        float rt[8];
        level2g<2, 6>(&lds[4][0], &lds[1][0], 518, rt);
        wr2g(&lds[3][0], 518, rt);
    }
    __syncthreads();

    // ---- Level 3: lo=buf3 (r2), hi=buf0 (cA_3), D=1 -> global, granules [7,519) ----
    level2g<1, 4>(&lds[3][0], &lds[0][0], 7 + 2 * tid, r);
    float* __restrict__ o = out + (size_t)row * T + t0 + (tid << 3);
    *(float4*)(o)     = make_float4(r[0], r[1], r[2], r[3]);
    *(float4*)(o + 4) = make_float4(r[4], r[5], r[6], r[7]);
}

extern "C" void kernel_launch(void* const* d_in, const int* in_sizes, int n_in,
                              void* d_out, int out_size, void* d_ws, size_t ws_size,
                              hipStream_t stream)
{
    const float* coeffs = (const float*)d_in[0];
    float* out = (float*)d_out;
    const int nrows = in_sizes[0] / (T * 4);   // 4096
    iswt_kernel<<<nrows * 2, 256, 0, stream>>>(coeffs, out);
}